// Round 9
// baseline (112.741 us; speedup 1.0000x reference)
//
#include <hip/hip_runtime.h>
#include <hip/hip_bf16.h>
#include <math.h>

// SLAYFeatures via MFMA: out[b, h*64 + n] = f(proj, r), n = r*32+m,
// proj = x_norm . omega[r,h,:,m].  x[B,H*D] fp32, omega[R,H,D,M] fp32.
// B=65536,H=16,D=64,M=32,R=2. N=R*M=64.
//
// omega in LDS as bf16 hi/lo planes [n][k] (XOR-swizzled), b128 frags;
// dot = mfma_f32_16x16x32_bf16 with 3-term hi/lo split (fp32-level accuracy).
// Operand roles: omega=A, x=B -> lane's acc[0..3] = 4 consecutive n of ONE
// row b -> float4 stores; per-lane rnorm is directly the right one.
//
// Round-8 lessons: manual prefetch is always defeated (compiler sinks pure
// loads; VGPR=36). Kernel is latency-bound at OccupancyPercent=52 because
// __launch_bounds__(256,4) itself caps residency at 4 blocks/CU. Resource
// use (VGPR 36, LDS 16KB) permits 8 blocks/CU, and the 64-VGPR cap of
// (256,8) is safely above the 36 this code needs (round-6's squeeze came
// from code needing ~64+). Grid 2048 = 8 x 256 CUs -> fully resident.

#define HH 16
#define DD 64
#define MM 32
#define RR 2
#define NN (RR*MM)          // 64 output cols per head
#define TILE_B 512
#define NST (TILE_B/64)     // 8 sub-tiles

using short8  = __attribute__((ext_vector_type(8))) short;
using floatx4 = __attribute__((ext_vector_type(4))) float;

__device__ __forceinline__ short bf16_hi(float v) {
    __hip_bfloat16 b = __float2bfloat16(v);      // RNE; pairs fuse to v_cvt_pk_bf16_f32
    return __builtin_bit_cast(short, b);
}
__device__ __forceinline__ float bf16_f(short s) {
    return __uint_as_float(((unsigned)(unsigned short)s) << 16);
}

__global__ __launch_bounds__(256, 8)
void slay_mfma_kernel(const float* __restrict__ x,
                      const float* __restrict__ omega,
                      const float* __restrict__ qn,
                      const float* __restrict__ qw,
                      float* __restrict__ out)
{
    __shared__ short lds_hi[NN * DD];   // [n][k] bf16 hi plane, swizzled (8KB)
    __shared__ short lds_lo[NN * DD];   // lo plane (8KB)

    const int tid  = threadIdx.x;
    const int lane = tid & 63;
    const int wv   = tid >> 6;
    const int h    = blockIdx.x & (HH - 1);
    const int tile = blockIdx.x >> 4;

    const int mrow = lane & 15;    // b-row index within wave tile
    const int g    = lane >> 4;    // k-group 0..3

    // ---- stage omega[.,h,.,.] -> LDS bf16 hi/lo planes [n=r*32+m][k=d] ----
    #pragma unroll
    for (int i = 0; i < (RR * DD * MM) / 256; ++i) {
        int e  = i * 256 + tid;
        int rr = e >> 11;
        int d  = (e >> 5) & (DD - 1);
        int m  = e & (MM - 1);
        float v = omega[((size_t)(rr * HH + h) * DD + d) * MM + m];
        short hi = bf16_hi(v);
        short lo = bf16_hi(v - bf16_f(hi));
        int n   = rr * MM + m;
        int byt = (d * 2) ^ ((n & 7) << 4);           // XOR swizzle within 128B row
        *(short*)((char*)lds_hi + n * (DD * 2) + byt) = hi;
        *(short*)((char*)lds_lo + n * (DD * 2) + byt) = lo;
    }
    __syncthreads();

    // quadrature scalars (uniform)
    const float sn[2]  = { qn[0], qn[1] };
    const float s2s[2] = { sqrtf(2.f * fmaxf(sn[0], 0.f)), sqrtf(2.f * fmaxf(sn[1], 0.f)) };
    const float cr[2]  = { sqrtf(fmaxf(qw[0], 0.f)) * (1.f / MM),
                           sqrtf(fmaxf(qw[1], 0.f)) * (1.f / MM) };

    const int sw = (mrow & 7) << 4;   // frag swizzle (LDS row n = nt*16+mrow)

    const float* xr0 = x + (size_t)(tile * TILE_B + wv * 16 + mrow) * (HH * DD) + h * DD;

    #pragma unroll
    for (int st = 0; st < NST; ++st) {
        const float* xr = xr0 + (size_t)st * 64 * (HH * DD);
        const int b_base = tile * TILE_B + st * 64 + wv * 16;

        // ---- load 16 x values: k = kc*32 + g*8 + {0..7} ----
        float xv[16];
        *(float4*)(xv + 0)  = *(const float4*)(xr + g * 8);
        *(float4*)(xv + 4)  = *(const float4*)(xr + g * 8 + 4);
        *(float4*)(xv + 8)  = *(const float4*)(xr + 32 + g * 8);
        *(float4*)(xv + 12) = *(const float4*)(xr + 32 + g * 8 + 4);

        // ---- fp32 row norm (sum split across the 4 k-groups) ----
        float ss = 0.f;
        #pragma unroll
        for (int j = 0; j < 16; ++j) ss = fmaf(xv[j], xv[j], ss);
        ss += __shfl_xor(ss, 16, 64);
        ss += __shfl_xor(ss, 32, 64);
        const float rnorm = 1.0f / fmaxf(sqrtf(ss), 1e-6f);  // row (b_base+mrow)

        // ---- bf16 hi/lo x fragments (B operand; raw x, norm in epilogue) ----
        short8 x_hi[2], x_lo[2];
        #pragma unroll
        for (int kc = 0; kc < 2; ++kc)
            #pragma unroll
            for (int j = 0; j < 8; ++j) {
                float v  = xv[kc * 8 + j];
                short hi = bf16_hi(v);
                x_hi[kc][j] = hi;
                x_lo[kc][j] = bf16_hi(v - bf16_f(hi));
            }

        #pragma unroll
        for (int nt = 0; nt < 4; ++nt) {
            const char* rh = (const char*)lds_hi + (nt * 16 + mrow) * (DD * 2);
            const char* rl = (const char*)lds_lo + (nt * 16 + mrow) * (DD * 2);
            const int k0 = (g * 16) ^ sw;
            const int k1 = (64 + g * 16) ^ sw;
            short8 oh0 = *(const short8*)(rh + k0);   // omega A-frag, hi plane
            short8 oh1 = *(const short8*)(rh + k1);
            short8 ol0 = *(const short8*)(rl + k0);   // lo plane
            short8 ol1 = *(const short8*)(rl + k1);

            floatx4 acc = {0.f, 0.f, 0.f, 0.f};
            acc = __builtin_amdgcn_mfma_f32_16x16x32_bf16(oh0, x_hi[0], acc, 0, 0, 0);
            acc = __builtin_amdgcn_mfma_f32_16x16x32_bf16(oh1, x_hi[1], acc, 0, 0, 0);
            acc = __builtin_amdgcn_mfma_f32_16x16x32_bf16(oh0, x_lo[0], acc, 0, 0, 0);
            acc = __builtin_amdgcn_mfma_f32_16x16x32_bf16(oh1, x_lo[1], acc, 0, 0, 0);
            acc = __builtin_amdgcn_mfma_f32_16x16x32_bf16(ol0, x_hi[0], acc, 0, 0, 0);
            acc = __builtin_amdgcn_mfma_f32_16x16x32_bf16(ol1, x_hi[1], acc, 0, 0, 0);

            // D[n][b]: lane holds n = nt*16 + g*4 + q for row b = b_base+mrow
            const int r = nt >> 1;
            floatx4 res;
            #pragma unroll
            for (int q = 0; q < 4; ++q) {
                float proj = acc[q] * rnorm;
                float ea = fmaf(proj, s2s[r], -sn[r]);
                ea = fminf(fmaxf(ea, -10.f), 10.f);
                res[q] = proj * proj * __expf(ea) * cr[r];
            }
            floatx4* op = (floatx4*)(out + (size_t)(b_base + mrow) * (HH * NN)
                                         + h * NN + nt * 16 + g * 4);
            __builtin_nontemporal_store(res, op);
        }
    }
}

extern "C" void kernel_launch(void* const* d_in, const int* in_sizes, int n_in,
                              void* d_out, int out_size, void* d_ws, size_t ws_size,
                              hipStream_t stream) {
    const float* x     = (const float*)d_in[0];
    const float* omega = (const float*)d_in[1];
    const float* qn    = (const float*)d_in[2];
    const float* qw    = (const float*)d_in[3];
    float* out = (float*)d_out;

    const int B = in_sizes[0] / (HH * DD);     // 65536
    dim3 grid((B / TILE_B) * HH);              // 2048 blocks; h = bid & 15
    dim3 block(256);

    slay_mfma_kernel<<<grid, block, 0, stream>>>(x, omega, qn, qw, out);
}

// Round 10
// 89.204 us; speedup vs baseline: 1.2639x; 1.2639x over previous
//
#include <hip/hip_runtime.h>
#include <hip/hip_bf16.h>
#include <math.h>

// SLAYFeatures via MFMA: out[b, h*64 + n] = f(proj, r), n = r*32+m,
// proj = x_norm . omega[r,h,:,m].  x[B,H*D] fp32, omega[R,H,D,M] fp32.
// B=65536,H=16,D=64,M=32,R=2. N=R*M=64.
//
// omega in LDS as bf16 hi/lo planes [n][k] (XOR-swizzled), b128 frags;
// dot = mfma_f32_16x16x32_bf16 with 3-term hi/lo split (fp32-level accuracy).
// omega=A, x=B -> lane's acc[0..3] = 4 consecutive n of ONE row b; per-lane
// rnorm is directly the right one.
//
// Round-9 lesson: occupancy 52->60% changed nothing (TLP-insensitive,
// ~4.2 TB/s effective) -> DRAM access-pattern bound. Reads are half
// L3-absorbed (FETCH=131MB); WRITES (268MB, can't be absorbed) went out as
// 16 scattered 64B segments per store instr with nt bypassing L2
// aggregation. Fix: per-wave LDS transpose bounce -> store instructions
// cover 4 x 256B contiguous segments instead of 16 x 64B.

#define HH 16
#define DD 64
#define MM 32
#define RR 2
#define NN (RR*MM)          // 64 output cols per head
#define TILE_B 512
#define NST (TILE_B/64)     // 8 sub-tiles

using short8  = __attribute__((ext_vector_type(8))) short;
using floatx4 = __attribute__((ext_vector_type(4))) float;

__device__ __forceinline__ short bf16_hi(float v) {
    __hip_bfloat16 b = __float2bfloat16(v);      // RNE; pairs fuse to v_cvt_pk_bf16_f32
    return __builtin_bit_cast(short, b);
}
__device__ __forceinline__ float bf16_f(short s) {
    return __uint_as_float(((unsigned)(unsigned short)s) << 16);
}

__global__ __launch_bounds__(256, 4)
void slay_mfma_kernel(const float* __restrict__ x,
                      const float* __restrict__ omega,
                      const float* __restrict__ qn,
                      const float* __restrict__ qw,
                      float* __restrict__ out)
{
    __shared__ short lds_hi[NN * DD];       // [n][k] bf16 hi plane, swizzled (8KB)
    __shared__ short lds_lo[NN * DD];       // lo plane (8KB)
    __shared__ float lds_oc[4][16 * 64];    // per-wave out bounce [16 rows][256B] (16KB)

    const int tid  = threadIdx.x;
    const int lane = tid & 63;
    const int wv   = tid >> 6;
    const int h    = blockIdx.x & (HH - 1);
    const int tile = blockIdx.x >> 4;

    const int mrow = lane & 15;    // b-row index within wave tile
    const int g    = lane >> 4;    // k-group 0..3

    // ---- stage omega[.,h,.,.] -> LDS bf16 hi/lo planes [n=r*32+m][k=d] ----
    #pragma unroll
    for (int i = 0; i < (RR * DD * MM) / 256; ++i) {
        int e  = i * 256 + tid;
        int rr = e >> 11;
        int d  = (e >> 5) & (DD - 1);
        int m  = e & (MM - 1);
        float v = omega[((size_t)(rr * HH + h) * DD + d) * MM + m];
        short hi = bf16_hi(v);
        short lo = bf16_hi(v - bf16_f(hi));
        int n   = rr * MM + m;
        int byt = (d * 2) ^ ((n & 7) << 4);           // XOR swizzle within 128B row
        *(short*)((char*)lds_hi + n * (DD * 2) + byt) = hi;
        *(short*)((char*)lds_lo + n * (DD * 2) + byt) = lo;
    }
    __syncthreads();

    // quadrature scalars (uniform)
    const float sn[2]  = { qn[0], qn[1] };
    const float s2s[2] = { sqrtf(2.f * fmaxf(sn[0], 0.f)), sqrtf(2.f * fmaxf(sn[1], 0.f)) };
    const float cr[2]  = { sqrtf(fmaxf(qw[0], 0.f)) * (1.f / MM),
                           sqrtf(fmaxf(qw[1], 0.f)) * (1.f / MM) };

    const int sw = (mrow & 7) << 4;   // frag swizzle (LDS row n = nt*16+mrow)
    char* const wb = (char*)lds_oc[wv];

    const float* xr0 = x + (size_t)(tile * TILE_B + wv * 16 + mrow) * (HH * DD) + h * DD;

    #pragma unroll
    for (int st = 0; st < NST; ++st) {
        const float* xr = xr0 + (size_t)st * 64 * (HH * DD);
        const int b_base = tile * TILE_B + st * 64 + wv * 16;

        // ---- load 16 x values: k = kc*32 + g*8 + {0..7} ----
        float xv[16];
        *(float4*)(xv + 0)  = *(const float4*)(xr + g * 8);
        *(float4*)(xv + 4)  = *(const float4*)(xr + g * 8 + 4);
        *(float4*)(xv + 8)  = *(const float4*)(xr + 32 + g * 8);
        *(float4*)(xv + 12) = *(const float4*)(xr + 32 + g * 8 + 4);

        // ---- fp32 row norm (sum split across the 4 k-groups) ----
        float ss = 0.f;
        #pragma unroll
        for (int j = 0; j < 16; ++j) ss = fmaf(xv[j], xv[j], ss);
        ss += __shfl_xor(ss, 16, 64);
        ss += __shfl_xor(ss, 32, 64);
        const float rnorm = 1.0f / fmaxf(sqrtf(ss), 1e-6f);  // row (b_base+mrow)

        // ---- bf16 hi/lo x fragments (B operand; raw x, norm in epilogue) ----
        short8 x_hi[2], x_lo[2];
        #pragma unroll
        for (int kc = 0; kc < 2; ++kc)
            #pragma unroll
            for (int j = 0; j < 8; ++j) {
                float v  = xv[kc * 8 + j];
                short hi = bf16_hi(v);
                x_hi[kc][j] = hi;
                x_lo[kc][j] = bf16_hi(v - bf16_f(hi));
            }

        #pragma unroll
        for (int nt = 0; nt < 4; ++nt) {
            const char* rh = (const char*)lds_hi + (nt * 16 + mrow) * (DD * 2);
            const char* rl = (const char*)lds_lo + (nt * 16 + mrow) * (DD * 2);
            const int k0 = (g * 16) ^ sw;
            const int k1 = (64 + g * 16) ^ sw;
            short8 oh0 = *(const short8*)(rh + k0);   // omega A-frag, hi plane
            short8 oh1 = *(const short8*)(rh + k1);
            short8 ol0 = *(const short8*)(rl + k0);   // lo plane
            short8 ol1 = *(const short8*)(rl + k1);

            floatx4 acc = {0.f, 0.f, 0.f, 0.f};
            acc = __builtin_amdgcn_mfma_f32_16x16x32_bf16(oh0, x_hi[0], acc, 0, 0, 0);
            acc = __builtin_amdgcn_mfma_f32_16x16x32_bf16(oh1, x_hi[1], acc, 0, 0, 0);
            acc = __builtin_amdgcn_mfma_f32_16x16x32_bf16(oh0, x_lo[0], acc, 0, 0, 0);
            acc = __builtin_amdgcn_mfma_f32_16x16x32_bf16(oh1, x_lo[1], acc, 0, 0, 0);
            acc = __builtin_amdgcn_mfma_f32_16x16x32_bf16(ol0, x_hi[0], acc, 0, 0, 0);
            acc = __builtin_amdgcn_mfma_f32_16x16x32_bf16(ol1, x_hi[1], acc, 0, 0, 0);

            // D[n][b]: lane holds n = nt*16 + g*4 + q for row b = b_base+mrow
            const int r = nt >> 1;
            floatx4 res;
            #pragma unroll
            for (int q = 0; q < 4; ++q) {
                float proj = acc[q] * rnorm;
                float ea = fmaf(proj, s2s[r], -sn[r]);
                ea = fminf(fmaxf(ea, -10.f), 10.f);
                res[q] = proj * proj * __expf(ea) * cr[r];
            }
            // bounce to per-wave LDS: row mrow, logical col byte nt*64+g*16,
            // XOR-swizzled by ((row&7)<<4)
            *(floatx4*)(wb + mrow * 256 + ((nt * 64 + g * 16) ^ sw)) = res;
        }

        // ---- transposed read-back + contiguous stores (4 x 256B per instr) ----
        #pragma unroll
        for (int i = 0; i < 4; ++i) {
            const int row = i * 4 + g;          // 0..15 across 4 instrs
            const int col = (mrow) * 16;        // byte col within 256B chunk
            floatx4 v = *(const floatx4*)(wb + row * 256 + (col ^ ((row & 7) << 4)));
            float* op = out + (size_t)(b_base + row) * (HH * NN) + h * NN + mrow * 4;
            __builtin_nontemporal_store(v, (floatx4*)op);
        }
    }
}

extern "C" void kernel_launch(void* const* d_in, const int* in_sizes, int n_in,
                              void* d_out, int out_size, void* d_ws, size_t ws_size,
                              hipStream_t stream) {
    const float* x     = (const float*)d_in[0];
    const float* omega = (const float*)d_in[1];
    const float* qn    = (const float*)d_in[2];
    const float* qw    = (const float*)d_in[3];
    float* out = (float*)d_out;

    const int B = in_sizes[0] / (HH * DD);     // 65536
    dim3 grid((B / TILE_B) * HH);              // 2048 blocks; h = bid & 15
    dim3 block(256);

    slay_mfma_kernel<<<grid, block, 0, stream>>>(x, omega, qn, qw, out);
}